// Round 14
// baseline (1190.916 us; speedup 1.0000x reference)
//
#include <hip/hip_runtime.h>
#include <math.h>

#define TPB 256
#define NVOX 32768
#define BN_EPS 1e-5f

typedef short s16x8 __attribute__((ext_vector_type(8)));
typedef short s16x4 __attribute__((ext_vector_type(4)));
typedef float f32x4 __attribute__((ext_vector_type(4)));

// ---------------- ws byte offsets ----------------
#define P0_OFF     0u
#define P1_OFF     256u
#define P2_OFF     (P1_OFF + 64u*128u*4u)
#define P3_OFF     (P2_OFF + 64u*256u*4u)
#define PAR_END    (P3_OFF + 64u*512u*4u)
#define A0_OFF     229632u
#define C0_OFF     229888u
#define A1_OFF     230144u
#define C1_OFF     230400u
#define A2_OFF     230656u
#define C2_OFF     231680u
#define A3_OFF     232704u
#define C3_OFF     233728u
#define HIST_OFF   234752u
#define BASE_OFF   (HIST_OFF + 131072u)
#define CURS_OFF   (BASE_OFF + 131328u)
#define WT1_OFF    (CURS_OFF + 131072u)
#define WT2_OFF    (WT1_OFF + 4096u)
#define WT3_OFF    (WT2_OFF + 16384u)
#define WT4_OFF    (WT3_OFF + 65536u)
#define X_OFF      4845568u                   // X bf16 [Npad][16], voxel-sorted

__device__ __forceinline__ unsigned short f2bf(float f) {   // RTNE
    unsigned u = __float_as_uint(f);
    u += 0x7FFFu + ((u >> 16) & 1u);
    return (unsigned short)(u >> 16);
}
__device__ __forceinline__ unsigned short f2bft(float f) {  // truncate (hot path)
    return (unsigned short)(__float_as_uint(f) >> 16);
}
__device__ __forceinline__ float bf2f(unsigned short h) {
    return __uint_as_float(((unsigned)h) << 16);
}

template<int ROWB>
__device__ __forceinline__ int swz(int row, int b) {
    constexpr int M = (ROWB >= 128) ? 7 : ((ROWB >= 64) ? 3 : 1);
    return row * ROWB + (b ^ ((row & M) << 4));
}

__device__ __forceinline__ s16x4 bn_relu_pack(f32x4 acc, f32x4 av, f32x4 cv) {
    s16x4 pk;
#pragma unroll
    for (int r = 0; r < 4; ++r) pk[r] = (short)f2bft(fmaxf(fmaf(acc[r], av[r], cv[r]), 0.f));
    return pk;
}

template<int NOUT>
__device__ __forceinline__ void stats_red(f32x4 ps, f32x4 pq, int ch, float* prow) {
#pragma unroll
    for (int m = 1; m <= 8; m <<= 1) {
#pragma unroll
        for (int r = 0; r < 4; ++r) { ps[r] += __shfl_xor(ps[r], m); pq[r] += __shfl_xor(pq[r], m); }
    }
    if ((threadIdx.x & 15) == 0) {
#pragma unroll
        for (int r = 0; r < 4; ++r) {
            atomicAdd(&prow[ch + r], ps[r]);
            atomicAdd(&prow[NOUT + ch + r], pq[r]);
        }
    }
}

// ---------------- prep kernels ----------------
__global__ void k_prepw(const float* __restrict__ W1, const float* __restrict__ W2,
                        const float* __restrict__ W3, const float* __restrict__ W4,
                        unsigned short* __restrict__ wt1, unsigned short* __restrict__ wt2,
                        unsigned short* __restrict__ wt3, unsigned short* __restrict__ wt4) {
    for (int i = blockIdx.x * blockDim.x + threadIdx.x; i < 108544;
         i += gridDim.x * blockDim.x) {
        if (i < 2048) {
            int n = i >> 5, k = i & 31;
            wt1[i] = (k < 9) ? f2bf(W1[k * 64 + n]) : (unsigned short)0;
        } else if (i < 10240) {
            int j = i - 2048; int n = j >> 6, k = j & 63;
            wt2[j] = f2bf(W2[k * 128 + n]);
        } else if (i < 43008) {
            int j = i - 10240; int n = j >> 7, k = j & 127;
            wt3[j] = f2bf(W3[k * 256 + n]);
        } else {
            int j = i - 43008; int n = j >> 8, k = j & 255;
            wt4[j] = f2bf(W4[k * 256 + n]);
        }
    }
}

// voxel histogram + raw-x moments S (9) and G = upper-tri of Σ x x^T (45)
__global__ void k_hist_stats(const int* __restrict__ coords, const float* __restrict__ feats,
                             int N, unsigned* __restrict__ hist, float* __restrict__ banks) {
    float S[9] = {0}, G[45] = {0};
    for (int i = blockIdx.x * blockDim.x + threadIdx.x; i < N;
         i += gridDim.x * blockDim.x) {
        int v = (coords[3 * i] << 10) | (coords[3 * i + 1] << 5) | coords[3 * i + 2];
        atomicAdd(&hist[v], 1u);
        const float* r = feats + (size_t)i * 9;
        float x[9];
#pragma unroll
        for (int c = 0; c < 9; ++c) { x[c] = r[c]; S[c] += x[c]; }
        int idx = 0;
#pragma unroll
        for (int c = 0; c < 9; ++c)
#pragma unroll
            for (int c2 = 0; c2 <= c; ++c2) { G[idx] = fmaf(x[c], x[c2], G[idx]); ++idx; }
    }
#pragma unroll
    for (int m = 1; m <= 32; m <<= 1) {
#pragma unroll
        for (int c = 0; c < 9; ++c) S[c] += __shfl_xor(S[c], m);
#pragma unroll
        for (int j = 0; j < 45; ++j) G[j] += __shfl_xor(G[j], m);
    }
    if ((threadIdx.x & 63) == 0) {
        float* b = banks + (size_t)(blockIdx.x & 63) * 54;
#pragma unroll
        for (int c = 0; c < 9; ++c) atomicAdd(&b[c], S[c]);
#pragma unroll
        for (int j = 0; j < 45; ++j) atomicAdd(&b[9 + j], G[j]);
    }
}

__global__ void k_fin0(const float* __restrict__ banks, float* __restrict__ SG,
                       const float* __restrict__ g0, const float* __restrict__ be0,
                       float* __restrict__ A0, float* __restrict__ C0, float n) {
    __shared__ float sg[54];
    const int t = threadIdx.x;
    if (t < 54) {
        float s = 0.f;
        for (int b = 0; b < 64; ++b) s += banks[b * 54 + t];
        sg[t] = s; SG[t] = s;
    }
    __syncthreads();
    if (t < 9) {
        float m = sg[t] / n;
        float v = sg[9 + t * (t + 1) / 2 + t] / n - m * m;
        float a = g0[t] * rsqrtf(v + BN_EPS);
        A0[t] = a; C0[t] = be0[t] - m * a;
    }
}

// analytic L1 stats
__global__ void k_fin1(const float* __restrict__ SG,
                       const float* __restrict__ A0, const float* __restrict__ C0,
                       const float* __restrict__ W1, const float* __restrict__ b1,
                       const float* __restrict__ g1, const float* __restrict__ be1,
                       float* __restrict__ A1, float* __restrict__ C1, float n) {
    __shared__ float Sz[9], Gz[81];
    const int t = threadIdx.x;
    if (t < 9) Sz[t] = A0[t] * SG[t] + n * C0[t];
    if (t < 81) {
        const int c = t / 9, c2 = t - 9 * (t / 9);
        const int i = c > c2 ? c : c2, j = c > c2 ? c2 : c;
        const float G = SG[9 + i * (i + 1) / 2 + j];
        Gz[t] = A0[c] * A0[c2] * G + A0[c] * SG[c] * C0[c2]
              + C0[c] * A0[c2] * SG[c2] + n * C0[c] * C0[c2];
    }
    __syncthreads();
    if (t < 64) {
        float wn[9];
#pragma unroll
        for (int c = 0; c < 9; ++c) wn[c] = W1[c * 64 + t];
        float su = 0.f, qq = 0.f;
#pragma unroll
        for (int c = 0; c < 9; ++c) {
            su = fmaf(wn[c], Sz[c], su);
#pragma unroll
            for (int c2 = 0; c2 < 9; ++c2) qq = fmaf(wn[c] * wn[c2], Gz[c * 9 + c2], qq);
        }
        const float bb = b1[t];
        const float mean = (su + n * bb) / n;
        const float q = qq + 2.f * bb * su + n * bb * bb;
        const float var = q / n - mean * mean;
        const float a = g1[t] * rsqrtf(var + BN_EPS);
        A1[t] = a;
        C1[t] = fmaf(a, bb, be1[t] - mean * a);
    }
}

__global__ void k_scan(const unsigned* __restrict__ hist, int* __restrict__ base,
                       unsigned* __restrict__ cursor, int N) {
    __shared__ unsigned part[1024];
    const int t = threadIdx.x;
    unsigned sum = 0;
    for (int j = 0; j < 32; ++j) sum += hist[t * 32 + j];
    part[t] = sum;
    __syncthreads();
    for (int d = 1; d < 1024; d <<= 1) {
        unsigned v = (t >= d) ? part[t - d] : 0u;
        __syncthreads();
        part[t] += v;
        __syncthreads();
    }
    unsigned run = part[t] - sum;
    for (int j = 0; j < 32; ++j) {
        unsigned h = hist[t * 32 + j];
        base[t * 32 + j] = (int)run;
        cursor[t * 32 + j] = run;
        run += h;
    }
    if (t == 1023) base[32768] = (int)run;
}

__global__ void k_scatter2(const int* __restrict__ coords, const float* __restrict__ feats,
                           int N, unsigned* __restrict__ cursor,
                           const float* __restrict__ A0, const float* __restrict__ C0,
                           unsigned short* __restrict__ Xg) {
    float a0[9], c0[9];
#pragma unroll
    for (int c = 0; c < 9; ++c) { a0[c] = A0[c]; c0[c] = C0[c]; }
    for (int i = blockIdx.x * blockDim.x + threadIdx.x; i < N;
         i += gridDim.x * blockDim.x) {
        int v = (coords[3 * i] << 10) | (coords[3 * i + 1] << 5) | coords[3 * i + 2];
        unsigned pos = atomicAdd(&cursor[v], 1u);
        const float* r = feats + (size_t)i * 9;
        s16x8 lo, hi;
#pragma unroll
        for (int c = 0; c < 8; ++c) lo[c] = (short)f2bf(fmaf(r[c], a0[c], c0[c]));
        hi = (s16x8){0, 0, 0, 0, 0, 0, 0, 0};
        hi[0] = (short)f2bf(fmaf(r[8], a0[8], c0[8]));
        *(s16x8*)(Xg + (size_t)pos * 16) = lo;
        *(s16x8*)(Xg + (size_t)pos * 16 + 8) = hi;
    }
}

__global__ void k_fin(const float* __restrict__ part, int nparts, int C,
                      const float* __restrict__ g, const float* __restrict__ be,
                      const float* __restrict__ bias,
                      float* __restrict__ A, float* __restrict__ Cc, float n) {
    int c = threadIdx.x;
    if (c >= C) return;
    float s = 0.f, q = 0.f;
    for (int r = 0; r < nparts; ++r) { s += part[r * 2 * C + c]; q += part[r * 2 * C + C + c]; }
    float m = s / n;
    float v = q / n - m * m;
    float a = g[c] * rsqrtf(v + BN_EPS);
    float cc = be[c] - m * a;
    A[c] = a;
    Cc[c] = bias ? fmaf(a, bias[c], cc) : cc;
}

__global__ void k_coords(float* __restrict__ outc) {
    int v = blockIdx.x * blockDim.x + threadIdx.x;
    if (v < NVOX) {
        outc[3 * v + 0] = (float)(v >> 10);
        outc[3 * v + 1] = (float)((v >> 5) & 31);
        outc[3 * v + 2] = (float)(v & 31);
    }
}

// =====================================================================
// pass2: X -> L1 -> L2 stats.  (unchanged)
// =====================================================================
__global__ __launch_bounds__(256) void k_pass2(
    const unsigned short* __restrict__ Xg,
    const unsigned short* __restrict__ wt1, const unsigned short* __restrict__ wt2,
    const float* __restrict__ A1, const float* __restrict__ C1,
    const float* __restrict__ b2,
    float* __restrict__ p2, int N, int nt) {
    __shared__ char act1[2][16384];
    const int tid = threadIdx.x;
    const int w = tid >> 6, lane = tid & 63, g = lane >> 4, lq = lane & 15;
    const int chb1 = w * 16, chb2 = w * 32;
    const int mask = (lq & 7) << 4;
    char* const a1w  = act1[0] + lq * 128 + (((chb1 + g * 4) * 2) ^ mask);
    char* const a1r0 = act1[0] + lq * 128 + ((g * 16) ^ mask);
    char* const a1r1 = act1[0] + lq * 128 + ((64 + g * 16) ^ mask);

    const s16x8 a1 = *(const s16x8*)(wt1 + (chb1 + lq) * 32 + g * 8);
    s16x8 w2f[2][2];
#pragma unroll
    for (int mt = 0; mt < 2; ++mt)
#pragma unroll
        for (int kc = 0; kc < 2; ++kc)
            w2f[mt][kc] = *(const s16x8*)(wt2 + (size_t)(chb2 + mt * 16 + lq) * 64 + kc * 32 + g * 8);
    const int ch1 = chb1 + g * 4;
    const f32x4 av1 = *(const f32x4*)(A1 + ch1);
    const f32x4 cv1 = *(const f32x4*)(C1 + ch1);
    f32x4 bv2[2];
#pragma unroll
    for (int mt = 0; mt < 2; ++mt) bv2[mt] = *(const f32x4*)(b2 + chb2 + mt * 16 + g * 4);
    f32x4 ps[2], pq[2];
#pragma unroll
    for (int mt = 0; mt < 2; ++mt) { ps[mt] = (f32x4){0.f,0.f,0.f,0.f}; pq[mt] = (f32x4){0.f,0.f,0.f,0.f}; }

    int t = blockIdx.x;
    if (t < nt) {
#pragma unroll
        for (int ct = 0; ct < 8; ++ct) {
            const s16x8 b = *(const s16x8*)(Xg + (size_t)(t * 128 + ct * 16 + lq) * 16 + g * 8);
            f32x4 a = (f32x4){0.f,0.f,0.f,0.f};
            a = __builtin_amdgcn_mfma_f32_16x16x32_bf16(a1, b, a, 0, 0, 0);
            *(s16x4*)(a1w + ct * 2048) = bn_relu_pack(a, av1, cv1);
        }
        __syncthreads();
        int cur = 0;
        while (true) {
            const int tn = t + gridDim.x;
            const bool more = tn < nt;
            const int t0 = t * 128;
            const int co = cur << 14;
            f32x4 acc2[2][8];
#pragma unroll
            for (int mt = 0; mt < 2; ++mt)
#pragma unroll
                for (int ct = 0; ct < 8; ++ct) acc2[mt][ct] = (f32x4){0.f,0.f,0.f,0.f};
#pragma unroll
            for (int kc = 0; kc < 2; ++kc) {
                char* const rb = (kc ? a1r1 : a1r0) + co;
#pragma unroll
                for (int ct = 0; ct < 8; ++ct) {
                    const s16x8 b = *(const s16x8*)(rb + ct * 2048);
#pragma unroll
                    for (int mt = 0; mt < 2; ++mt)
                        acc2[mt][ct] = __builtin_amdgcn_mfma_f32_16x16x32_bf16(w2f[mt][kc], b, acc2[mt][ct], 0, 0, 0);
                }
            }
#pragma unroll
            for (int mt = 0; mt < 2; ++mt)
#pragma unroll
                for (int ct = 0; ct < 8; ++ct) {
                    const bool valid = (t0 + ct * 16 + lq) < N;
#pragma unroll
                    for (int r = 0; r < 4; ++r) {
                        const float h = valid ? (acc2[mt][ct][r] + bv2[mt][r]) : 0.f;
                        ps[mt][r] += h; pq[mt][r] += h * h;
                    }
                }
            if (more) {
                char* const wb = a1w + (co ^ 16384);
#pragma unroll
                for (int ct = 0; ct < 8; ++ct) {
                    const s16x8 b = *(const s16x8*)(Xg + (size_t)(tn * 128 + ct * 16 + lq) * 16 + g * 8);
                    f32x4 a = (f32x4){0.f,0.f,0.f,0.f};
                    a = __builtin_amdgcn_mfma_f32_16x16x32_bf16(a1, b, a, 0, 0, 0);
                    *(s16x4*)(wb + ct * 2048) = bn_relu_pack(a, av1, cv1);
                }
            }
            __syncthreads();
            if (!more) break;
            t = tn; cur ^= 1;
        }
    }
    float* prow = p2 + (blockIdx.x & 63) * 256;
#pragma unroll
    for (int mt = 0; mt < 2; ++mt)
        stats_red<128>(ps[mt], pq[mt], chb2 + mt * 16 + g * 4, prow);
}

// =====================================================================
// pass3: X -> L1 -> L2 -> L3 stats.  (unchanged)
// =====================================================================
__global__ __launch_bounds__(512) void k_pass3(
    const unsigned short* __restrict__ Xg,
    const unsigned short* __restrict__ wt1, const unsigned short* __restrict__ wt2,
    const unsigned short* __restrict__ wt3,
    const float* __restrict__ A1, const float* __restrict__ C1,
    const float* __restrict__ A2, const float* __restrict__ C2,
    const float* __restrict__ b3,
    float* __restrict__ p3, int N, int nt) {
    __shared__ char act1[8192];
    __shared__ char act2[16384];
    const int tid = threadIdx.x;
    const int w = tid >> 6, lane = tid & 63, g = lane >> 4, lq = lane & 15;
    const int wm = w >> 1, wn = w & 1;
    const int chb1 = wm * 16, chb2 = w * 16, chb3 = w * 32;
    const int mask = (lq & 7) << 4;
    char* const a1w  = act1 + (wn * 32 + lq) * 128 + (((chb1 + g * 4) * 2) ^ mask);
    char* const a1r0 = act1 + lq * 128 + ((g * 16) ^ mask);
    char* const a1r1 = act1 + lq * 128 + ((64 + g * 16) ^ mask);
    char* const a2w  = act2 + lq * 256 + (((chb2 + g * 4) * 2) ^ mask);
    char* const a2r0 = act2 + lq * 256 + ((g * 16) ^ mask);
    char* const a2r1 = act2 + lq * 256 + ((64 + g * 16) ^ mask);

    const s16x8 a1 = *(const s16x8*)(wt1 + (chb1 + lq) * 32 + g * 8);
    s16x8 w2f[2], w3f[2][4];
#pragma unroll
    for (int kc = 0; kc < 2; ++kc)
        w2f[kc] = *(const s16x8*)(wt2 + (size_t)(chb2 + lq) * 64 + kc * 32 + g * 8);
#pragma unroll
    for (int mt = 0; mt < 2; ++mt)
#pragma unroll
        for (int kc = 0; kc < 4; ++kc)
            w3f[mt][kc] = *(const s16x8*)(wt3 + (size_t)(chb3 + mt * 16 + lq) * 128 + kc * 32 + g * 8);
    const int ch1 = chb1 + g * 4, ch2 = chb2 + g * 4;
    const f32x4 av1 = *(const f32x4*)(A1 + ch1);
    const f32x4 cv1 = *(const f32x4*)(C1 + ch1);
    const f32x4 av2 = *(const f32x4*)(A2 + ch2);
    const f32x4 cv2 = *(const f32x4*)(C2 + ch2);
    f32x4 bv3[2];
#pragma unroll
    for (int mt = 0; mt < 2; ++mt) bv3[mt] = *(const f32x4*)(b3 + chb3 + mt * 16 + g * 4);
    f32x4 ps[2], pq[2];
#pragma unroll
    for (int mt = 0; mt < 2; ++mt) { ps[mt] = (f32x4){0.f,0.f,0.f,0.f}; pq[mt] = (f32x4){0.f,0.f,0.f,0.f}; }

    int t = blockIdx.x;
    if (t < nt) {
#pragma unroll
        for (int ct = 0; ct < 2; ++ct) {
            const int row = wn * 32 + ct * 16 + lq;
            const s16x8 b = *(const s16x8*)(Xg + (size_t)(t * 64 + row) * 16 + g * 8);
            f32x4 a = (f32x4){0.f,0.f,0.f,0.f};
            a = __builtin_amdgcn_mfma_f32_16x16x32_bf16(a1, b, a, 0, 0, 0);
            *(s16x4*)(a1w + ct * 2048) = bn_relu_pack(a, av1, cv1);
        }
        __syncthreads();
        {
            f32x4 acc[4];
#pragma unroll
            for (int ct = 0; ct < 4; ++ct) acc[ct] = (f32x4){0.f,0.f,0.f,0.f};
#pragma unroll
            for (int kc = 0; kc < 2; ++kc) {
                char* const rb = kc ? a1r1 : a1r0;
#pragma unroll
                for (int ct = 0; ct < 4; ++ct) {
                    const s16x8 b = *(const s16x8*)(rb + ct * 2048);
                    acc[ct] = __builtin_amdgcn_mfma_f32_16x16x32_bf16(w2f[kc], b, acc[ct], 0, 0, 0);
                }
            }
#pragma unroll
            for (int ct = 0; ct < 4; ++ct)
                *(s16x4*)(a2w + ct * 4096) = bn_relu_pack(acc[ct], av2, cv2);
        }
        __syncthreads();
        while (true) {
            const int tn = t + gridDim.x;
            const bool more = tn < nt;
            s16x8 xb[2];
            if (more) {
#pragma unroll
                for (int ct = 0; ct < 2; ++ct) {
                    const int row = wn * 32 + ct * 16 + lq;
                    xb[ct] = *(const s16x8*)(Xg + (size_t)(tn * 64 + row) * 16 + g * 8);
                }
            }
            {
                f32x4 acc[2][4];
#pragma unroll
                for (int mt = 0; mt < 2; ++mt)
#pragma unroll
                    for (int ct = 0; ct < 4; ++ct) acc[mt][ct] = (f32x4){0.f,0.f,0.f,0.f};
#pragma unroll
                for (int kc = 0; kc < 4; ++kc) {
                    char* const rb = ((kc & 1) ? a2r1 : a2r0) + (kc >> 1) * 128;
#pragma unroll
                    for (int ct = 0; ct < 4; ++ct) {
                        const s16x8 b = *(const s16x8*)(rb + ct * 4096);
#pragma unroll
                        for (int mt = 0; mt < 2; ++mt)
                            acc[mt][ct] = __builtin_amdgcn_mfma_f32_16x16x32_bf16(w3f[mt][kc], b, acc[mt][ct], 0, 0, 0);
                    }
                }
                const int t0 = t * 64;
#pragma unroll
                for (int mt = 0; mt < 2; ++mt)
#pragma unroll
                    for (int ct = 0; ct < 4; ++ct) {
                        const bool valid = (t0 + ct * 16 + lq) < N;
#pragma unroll
                        for (int r = 0; r < 4; ++r) {
                            const float h = valid ? (acc[mt][ct][r] + bv3[mt][r]) : 0.f;
                            ps[mt][r] += h; pq[mt][r] += h * h;
                        }
                    }
            }
            if (more) {
#pragma unroll
                for (int ct = 0; ct < 2; ++ct) {
                    f32x4 a = (f32x4){0.f,0.f,0.f,0.f};
                    a = __builtin_amdgcn_mfma_f32_16x16x32_bf16(a1, xb[ct], a, 0, 0, 0);
                    *(s16x4*)(a1w + ct * 2048) = bn_relu_pack(a, av1, cv1);
                }
            }
            __syncthreads();
            if (more) {
                f32x4 acc[4];
#pragma unroll
                for (int ct = 0; ct < 4; ++ct) acc[ct] = (f32x4){0.f,0.f,0.f,0.f};
#pragma unroll
                for (int kc = 0; kc < 2; ++kc) {
                    char* const rb = kc ? a1r1 : a1r0;
#pragma unroll
                    for (int ct = 0; ct < 4; ++ct) {
                        const s16x8 b = *(const s16x8*)(rb + ct * 2048);
                        acc[ct] = __builtin_amdgcn_mfma_f32_16x16x32_bf16(w2f[kc], b, acc[ct], 0, 0, 0);
                    }
                }
#pragma unroll
                for (int ct = 0; ct < 4; ++ct)
                    *(s16x4*)(a2w + ct * 4096) = bn_relu_pack(acc[ct], av2, cv2);
            }
            __syncthreads();
            if (!more) break;
            t = tn;
        }
    }
    float* prow = p3 + (blockIdx.x & 63) * 512;
#pragma unroll
    for (int mt = 0; mt < 2; ++mt)
        stats_red<256>(ps[mt], pq[mt], chb3 + mt * 16 + g * 4, prow);
}

// =====================================================================
// pass4: X -> L1..L4 -> segment max.  1024 thr / 16 waves.
// L4 K-split with DUAL partial buffers (h4a=kh0+bias, h4b=kh1);
// segmax sums both.  2 barriers/tile, no cross-barrier accumulators.
// =====================================================================
__global__ __launch_bounds__(1024, 4) void k_pass4(
    const unsigned short* __restrict__ Xg,
    const unsigned short* __restrict__ wt1, const unsigned short* __restrict__ wt2,
    const unsigned short* __restrict__ wt3, const unsigned short* __restrict__ wt4,
    const float* __restrict__ A1, const float* __restrict__ C1,
    const float* __restrict__ A2, const float* __restrict__ C2,
    const float* __restrict__ A3, const float* __restrict__ C3,
    const float* __restrict__ b4,
    const int* __restrict__ base, float* __restrict__ out) {
    extern __shared__ char smem[];
    char* act1 = smem;                  // 8K  [64][128B]
    char* act2 = smem + 8192;           // 16K [64][256B]
    char* act3 = smem + 24576;          // 32K [64][512B]
    char* h4a  = smem + 57344;          // 32K [64][512B] (kh0 partial + bias)
    char* h4b  = smem + 90112;          // 32K [64][512B] (kh1 partial)

    const int tid = threadIdx.x;
    const int w = tid >> 6, lane = tid & 63, g = lane >> 4, lq = lane & 15;
    const int c1 = (w & 3) * 16, p1 = (w >> 2) * 16;   // L1 roles
    const int c2 = (w & 7) * 16, p2 = (w >> 3) * 32;   // L2 roles
    const int c3 = w * 16;                             // L3 role
    const int c4 = (w & 7) * 32, kh = w >> 3;          // L4 role: 32ch, K-half
    const int mask = (lq & 7) << 4;
    char* const a1w  = act1 + (p1 + lq) * 128 + (((c1 + g * 4) * 2) ^ mask);
    char* const a1r0 = act1 + (p2 + lq) * 128 + ((g * 16) ^ mask);
    char* const a1r1 = act1 + (p2 + lq) * 128 + ((64 + g * 16) ^ mask);
    char* const a2w  = act2 + (p2 + lq) * 256 + (((c2 + g * 4) * 2) ^ mask);
    char* const a2r0 = act2 + lq * 256 + ((g * 16) ^ mask);
    char* const a2r1 = act2 + lq * 256 + ((64 + g * 16) ^ mask);
    char* const a3w  = act3 + lq * 512 + (((c3 + g * 4) * 2) ^ mask);
    char* const a3r0 = act3 + lq * 512 + ((kh * 256 + g * 16) ^ mask);
    char* const a3r1 = act3 + lq * 512 + ((kh * 256 + 64 + g * 16) ^ mask);
    // h4 write bases on own buffer; mt folded INSIDE the XOR
    char* const hb   = kh ? h4b : h4a;
    char* const h4w0 = hb + lq * 512 + (((c4 + g * 4) * 2) ^ mask);
    char* const h4w1 = hb + lq * 512 + (((c4 + 16 + g * 4) * 2) ^ mask);

    const int vb = blockIdx.x * 32;
    const int pstart = base[vb], pend = base[vb + 32];
    const int chgrp = tid & 31, slot = tid >> 5;
    const int vlo = base[vb + slot], vhi = base[vb + slot + 1];

    const s16x8 a1 = *(const s16x8*)(wt1 + (c1 + lq) * 32 + g * 8);
    s16x8 w2f[2], w3f[4], w4f[2][4];
#pragma unroll
    for (int kc = 0; kc < 2; ++kc)
        w2f[kc] = *(const s16x8*)(wt2 + (size_t)(c2 + lq) * 64 + kc * 32 + g * 8);
#pragma unroll
    for (int kc = 0; kc < 4; ++kc)
        w3f[kc] = *(const s16x8*)(wt3 + (size_t)(c3 + lq) * 128 + kc * 32 + g * 8);
#pragma unroll
    for (int mt = 0; mt < 2; ++mt)
#pragma unroll
        for (int kc = 0; kc < 4; ++kc)
            w4f[mt][kc] = *(const s16x8*)(wt4 + (size_t)(c4 + mt * 16 + lq) * 256 + kh * 128 + kc * 32 + g * 8);

    const f32x4 av1 = *(const f32x4*)(A1 + c1 + g * 4);
    const f32x4 cv1 = *(const f32x4*)(C1 + c1 + g * 4);
    const f32x4 av2 = *(const f32x4*)(A2 + c2 + g * 4);
    const f32x4 cv2 = *(const f32x4*)(C2 + c2 + g * 4);
    const f32x4 av3 = *(const f32x4*)(A3 + c3 + g * 4);
    const f32x4 cv3 = *(const f32x4*)(C3 + c3 + g * 4);
    f32x4 bv4[2];
#pragma unroll
    for (int mt = 0; mt < 2; ++mt) bv4[mt] = *(const f32x4*)(b4 + c4 + mt * 16 + g * 4);

    float rmax[8];
#pragma unroll
    for (int j = 0; j < 8; ++j) rmax[j] = -INFINITY;

    if (pstart < pend) {
        {
            const s16x8 b = *(const s16x8*)(Xg + (size_t)(pstart + p1 + lq) * 16 + g * 8);
            f32x4 a = (f32x4){0.f,0.f,0.f,0.f};
            a = __builtin_amdgcn_mfma_f32_16x16x32_bf16(a1, b, a, 0, 0, 0);
            *(s16x4*)a1w = bn_relu_pack(a, av1, cv1);
        }
        __syncthreads();
        {
            f32x4 acc[2];
#pragma unroll
            for (int ct = 0; ct < 2; ++ct) acc[ct] = (f32x4){0.f,0.f,0.f,0.f};
#pragma unroll
            for (int kc = 0; kc < 2; ++kc) {
                char* const rb = kc ? a1r1 : a1r0;
#pragma unroll
                for (int ct = 0; ct < 2; ++ct) {
                    const s16x8 b = *(const s16x8*)(rb + ct * 2048);
                    acc[ct] = __builtin_amdgcn_mfma_f32_16x16x32_bf16(w2f[kc], b, acc[ct], 0, 0, 0);
                }
            }
#pragma unroll
            for (int ct = 0; ct < 2; ++ct)
                *(s16x4*)(a2w + ct * 4096) = bn_relu_pack(acc[ct], av2, cv2);
        }
        __syncthreads();

        int lt = pstart;
        for (int t0 = pstart; t0 < pend; t0 += 64) {
            const int nxt = t0 + 64;
            const bool more = nxt < pend;
            // ===== phase A: L3(t0) + segmax(t0-64) + X/L1(nxt) =====
            s16x8 xb;
            if (more)
                xb = *(const s16x8*)(Xg + (size_t)(nxt + p1 + lq) * 16 + g * 8);
            {
                f32x4 acc[4];
#pragma unroll
                for (int ct = 0; ct < 4; ++ct) acc[ct] = (f32x4){0.f,0.f,0.f,0.f};
#pragma unroll
                for (int kc = 0; kc < 4; ++kc) {
                    char* const rb = ((kc & 1) ? a2r1 : a2r0) + (kc >> 1) * 128;
#pragma unroll
                    for (int ct = 0; ct < 4; ++ct) {
                        const s16x8 b = *(const s16x8*)(rb + ct * 4096);
                        acc[ct] = __builtin_amdgcn_mfma_f32_16x16x32_bf16(w3f[kc], b, acc[ct], 0, 0, 0);
                    }
                }
#pragma unroll
                for (int ct = 0; ct < 4; ++ct)
                    *(s16x4*)(a3w + ct * 8192) = bn_relu_pack(acc[ct], av3, cv3);
            }
            if (t0 > pstart) {
                const int tm = t0 - 64;
                const int lo = max(vlo, tm), hi = min(vhi, tm + 64);
                for (int p = lo; p < hi; ++p) {
                    const int row = p - tm;
                    const int off = row * 512 + ((chgrp * 16) ^ ((row & 7) << 4));
                    const s16x8 ha = *(const s16x8*)(h4a + off);
                    const s16x8 hbv = *(const s16x8*)(h4b + off);
#pragma unroll
                    for (int j = 0; j < 8; ++j)
                        rmax[j] = fmaxf(rmax[j],
                            bf2f((unsigned short)ha[j]) + bf2f((unsigned short)hbv[j]));
                }
            }
            if (more) {
                f32x4 a = (f32x4){0.f,0.f,0.f,0.f};
                a = __builtin_amdgcn_mfma_f32_16x16x32_bf16(a1, xb, a, 0, 0, 0);
                *(s16x4*)a1w = bn_relu_pack(a, av1, cv1);
            }
            __syncthreads();
            // ===== phase B: L2(nxt) + L4-partial(t0) -> own h4 buffer =====
            if (more) {
                f32x4 acc[2];
#pragma unroll
                for (int ct = 0; ct < 2; ++ct) acc[ct] = (f32x4){0.f,0.f,0.f,0.f};
#pragma unroll
                for (int kc = 0; kc < 2; ++kc) {
                    char* const rb = kc ? a1r1 : a1r0;
#pragma unroll
                    for (int ct = 0; ct < 2; ++ct) {
                        const s16x8 b = *(const s16x8*)(rb + ct * 2048);
                        acc[ct] = __builtin_amdgcn_mfma_f32_16x16x32_bf16(w2f[kc], b, acc[ct], 0, 0, 0);
                    }
                }
#pragma unroll
                for (int ct = 0; ct < 2; ++ct)
                    *(s16x4*)(a2w + ct * 4096) = bn_relu_pack(acc[ct], av2, cv2);
            }
            {
                f32x4 acc4[2][4];
#pragma unroll
                for (int mt = 0; mt < 2; ++mt)
#pragma unroll
                    for (int ct = 0; ct < 4; ++ct) acc4[mt][ct] = (f32x4){0.f,0.f,0.f,0.f};
#pragma unroll
                for (int kc = 0; kc < 4; ++kc) {
                    char* const rb = ((kc & 1) ? a3r1 : a3r0) + (kc >> 1) * 128;
#pragma unroll
                    for (int ct = 0; ct < 4; ++ct) {
                        const s16x8 b = *(const s16x8*)(rb + ct * 8192);
#pragma unroll
                        for (int mt = 0; mt < 2; ++mt)
                            acc4[mt][ct] = __builtin_amdgcn_mfma_f32_16x16x32_bf16(w4f[mt][kc], b, acc4[mt][ct], 0, 0, 0);
                    }
                }
                // pack to own buffer; kh0 folds bias, kh1 raw partial
#pragma unroll
                for (int mt = 0; mt < 2; ++mt) {
                    char* const hw = mt ? h4w1 : h4w0;
#pragma unroll
                    for (int ct = 0; ct < 4; ++ct) {
                        s16x4 pk;
#pragma unroll
                        for (int r = 0; r < 4; ++r) {
                            const float v = kh ? acc4[mt][ct][r] : (acc4[mt][ct][r] + bv4[mt][r]);
                            pk[r] = (short)f2bf(v);
                        }
                        *(s16x4*)(hw + ct * 8192) = pk;
                    }
                }
            }
            __syncthreads();
            lt = t0;
        }
        // drain
        {
            const int lo = max(vlo, lt), hi = min(vhi, lt + 64);
            for (int p = lo; p < hi; ++p) {
                const int row = p - lt;
                const int off = row * 512 + ((chgrp * 16) ^ ((row & 7) << 4));
                const s16x8 ha = *(const s16x8*)(h4a + off);
                const s16x8 hbv = *(const s16x8*)(h4b + off);
#pragma unroll
                for (int j = 0; j < 8; ++j)
                    rmax[j] = fmaxf(rmax[j],
                        bf2f((unsigned short)ha[j]) + bf2f((unsigned short)hbv[j]));
            }
        }
    }
    float* orow = out + (size_t)(vb + slot) * 256 + chgrp * 8;
    f32x4 o0, o1;
#pragma unroll
    for (int j = 0; j < 4; ++j) { o0[j] = rmax[j]; o1[j] = rmax[4 + j]; }
    *(f32x4*)orow = o0;
    *(f32x4*)(orow + 4) = o1;
}

extern "C" void kernel_launch(void* const* d_in, const int* in_sizes, int n_in,
                              void* d_out, int out_size, void* d_ws, size_t ws_size,
                              hipStream_t stream) {
    const float* feats = (const float*)d_in[0];
    const int* coords = (const int*)d_in[1];
    const float* g0 = (const float*)d_in[3];
    const float* be0 = (const float*)d_in[4];
    const float* W1 = (const float*)d_in[5];
    const float* b1 = (const float*)d_in[6];
    const float* g1 = (const float*)d_in[7];
    const float* be1 = (const float*)d_in[8];
    const float* W2 = (const float*)d_in[9];
    const float* b2 = (const float*)d_in[10];
    const float* g2 = (const float*)d_in[11];
    const float* be2 = (const float*)d_in[12];
    const float* W3 = (const float*)d_in[13];
    const float* b3 = (const float*)d_in[14];
    const float* g3 = (const float*)d_in[15];
    const float* be3 = (const float*)d_in[16];
    const float* W4 = (const float*)d_in[17];
    const float* b4 = (const float*)d_in[18];
    float* out = (float*)d_out;
    char* ws = (char*)d_ws;

    const int N = in_sizes[0] / 9;
    const float fN = (float)N;
    const int nt128 = (N + 127) / 128;
    const int nt64 = (N + 63) / 64;

    unsigned short* Xg = (unsigned short*)(ws + X_OFF);
    const unsigned short* wt1 = (const unsigned short*)(ws + WT1_OFF);
    const unsigned short* wt2 = (const unsigned short*)(ws + WT2_OFF);
    const unsigned short* wt3 = (const unsigned short*)(ws + WT3_OFF);
    const unsigned short* wt4 = (const unsigned short*)(ws + WT4_OFF);
    float* A0 = (float*)(ws + A0_OFF); float* C0 = (float*)(ws + C0_OFF);
    float* A1 = (float*)(ws + A1_OFF); float* C1 = (float*)(ws + C1_OFF);
    float* A2 = (float*)(ws + A2_OFF); float* C2 = (float*)(ws + C2_OFF);
    float* A3 = (float*)(ws + A3_OFF); float* C3 = (float*)(ws + C3_OFF);

    hipMemsetAsync(ws, 0, PAR_END, stream);
    hipMemsetAsync(ws + HIST_OFF, 0, 131072, stream);
    {   // zero X padding rows (pass kernels may read past N)
        const size_t rows = (size_t)nt128 * 128;
        hipMemsetAsync(ws + X_OFF + (size_t)N * 32u, 0,
                       (rows - (size_t)N) * 32u + 8192u, stream);
    }

    hipFuncSetAttribute((const void*)k_pass4,
        hipFuncAttributeMaxDynamicSharedMemorySize, 122880);

    k_prepw<<<128, TPB, 0, stream>>>(W1, W2, W3, W4,
        (unsigned short*)(ws + WT1_OFF), (unsigned short*)(ws + WT2_OFF),
        (unsigned short*)(ws + WT3_OFF), (unsigned short*)(ws + WT4_OFF));
    k_hist_stats<<<1024, TPB, 0, stream>>>(coords, feats, N,
        (unsigned*)(ws + HIST_OFF), (float*)(ws + P1_OFF));
    k_fin0<<<1, 64, 0, stream>>>((const float*)(ws + P1_OFF), (float*)(ws + P0_OFF),
                                 g0, be0, A0, C0, fN);
    k_fin1<<<1, 128, 0, stream>>>((const float*)(ws + P0_OFF), A0, C0,
                                  W1, b1, g1, be1, A1, C1, fN);
    k_scan<<<1, 1024, 0, stream>>>((const unsigned*)(ws + HIST_OFF),
                                   (int*)(ws + BASE_OFF), (unsigned*)(ws + CURS_OFF), N);
    k_scatter2<<<1024, TPB, 0, stream>>>(coords, feats, N, (unsigned*)(ws + CURS_OFF),
                                         A0, C0, Xg);
    k_coords<<<(NVOX + TPB - 1) / TPB, TPB, 0, stream>>>(out + (size_t)NVOX * 256);

    k_pass2<<<2048, 256, 0, stream>>>(Xg, wt1, wt2, A1, C1, b2,
                                      (float*)(ws + P2_OFF), N, nt128);
    k_fin<<<1, TPB, 0, stream>>>((const float*)(ws + P2_OFF), 64, 128, g2, be2, b2,
                                 A2, C2, fN);

    k_pass3<<<2048, 512, 0, stream>>>(Xg, wt1, wt2, wt3, A1, C1, A2, C2, b3,
                                      (float*)(ws + P3_OFF), N, nt64);
    k_fin<<<1, TPB, 0, stream>>>((const float*)(ws + P3_OFF), 64, 256, g3, be3, b3,
                                 A3, C3, fN);

    k_pass4<<<NVOX / 32, 1024, 122880, stream>>>(Xg, wt1, wt2, wt3, wt4,
        A1, C1, A2, C2, A3, C3, b4, (const int*)(ws + BASE_OFF), out);
}

// Round 15
// 931.684 us; speedup vs baseline: 1.2782x; 1.2782x over previous
//
#include <hip/hip_runtime.h>
#include <math.h>

#define TPB 256
#define NVOX 32768
#define BN_EPS 1e-5f

typedef short s16x8 __attribute__((ext_vector_type(8)));
typedef short s16x4 __attribute__((ext_vector_type(4)));
typedef float f32x4 __attribute__((ext_vector_type(4)));

// ---------------- ws byte offsets ----------------
#define P0_OFF     0u
#define P1_OFF     256u
#define P2_OFF     (P1_OFF + 64u*128u*4u)
#define P3_OFF     (P2_OFF + 64u*256u*4u)
#define PAR_END    (P3_OFF + 64u*512u*4u)
#define A0_OFF     229632u
#define C0_OFF     229888u
#define A1_OFF     230144u
#define C1_OFF     230400u
#define A2_OFF     230656u
#define C2_OFF     231680u
#define A3_OFF     232704u
#define C3_OFF     233728u
#define HIST_OFF   234752u
#define BASE_OFF   (HIST_OFF + 131072u)
#define CURS_OFF   (BASE_OFF + 131328u)
#define WT1_OFF    (CURS_OFF + 131072u)
#define WT2_OFF    (WT1_OFF + 4096u)
#define WT3_OFF    (WT2_OFF + 16384u)
#define WT4_OFF    (WT3_OFF + 65536u)
#define X_OFF      4845568u                   // X bf16 [Npad][16], voxel-sorted

__device__ __forceinline__ unsigned short f2bf(float f) {   // RTNE
    unsigned u = __float_as_uint(f);
    u += 0x7FFFu + ((u >> 16) & 1u);
    return (unsigned short)(u >> 16);
}
__device__ __forceinline__ unsigned short f2bft(float f) {  // truncate (hot path)
    return (unsigned short)(__float_as_uint(f) >> 16);
}
__device__ __forceinline__ float bf2f(unsigned short h) {
    return __uint_as_float(((unsigned)h) << 16);
}

template<int ROWB>
__device__ __forceinline__ int swz(int row, int b) {
    constexpr int M = (ROWB >= 128) ? 7 : ((ROWB >= 64) ? 3 : 1);
    return row * ROWB + (b ^ ((row & M) << 4));
}

__device__ __forceinline__ s16x4 bn_relu_pack(f32x4 acc, f32x4 av, f32x4 cv) {
    s16x4 pk;
#pragma unroll
    for (int r = 0; r < 4; ++r) pk[r] = (short)f2bft(fmaxf(fmaf(acc[r], av[r], cv[r]), 0.f));
    return pk;
}

template<int NOUT>
__device__ __forceinline__ void stats_red(f32x4 ps, f32x4 pq, int ch, float* prow) {
#pragma unroll
    for (int m = 1; m <= 8; m <<= 1) {
#pragma unroll
        for (int r = 0; r < 4; ++r) { ps[r] += __shfl_xor(ps[r], m); pq[r] += __shfl_xor(pq[r], m); }
    }
    if ((threadIdx.x & 15) == 0) {
#pragma unroll
        for (int r = 0; r < 4; ++r) {
            atomicAdd(&prow[ch + r], ps[r]);
            atomicAdd(&prow[NOUT + ch + r], pq[r]);
        }
    }
}

// ---------------- prep kernels ----------------
__global__ void k_prepw(const float* __restrict__ W1, const float* __restrict__ W2,
                        const float* __restrict__ W3, const float* __restrict__ W4,
                        unsigned short* __restrict__ wt1, unsigned short* __restrict__ wt2,
                        unsigned short* __restrict__ wt3, unsigned short* __restrict__ wt4) {
    for (int i = blockIdx.x * blockDim.x + threadIdx.x; i < 108544;
         i += gridDim.x * blockDim.x) {
        if (i < 2048) {
            int n = i >> 5, k = i & 31;
            wt1[i] = (k < 9) ? f2bf(W1[k * 64 + n]) : (unsigned short)0;
        } else if (i < 10240) {
            int j = i - 2048; int n = j >> 6, k = j & 63;
            wt2[j] = f2bf(W2[k * 128 + n]);
        } else if (i < 43008) {
            int j = i - 10240; int n = j >> 7, k = j & 127;
            wt3[j] = f2bf(W3[k * 256 + n]);
        } else {
            int j = i - 43008; int n = j >> 8, k = j & 255;
            wt4[j] = f2bf(W4[k * 256 + n]);
        }
    }
}

// voxel histogram + raw-x moments S (9) and G = upper-tri of Σ x x^T (45)
__global__ void k_hist_stats(const int* __restrict__ coords, const float* __restrict__ feats,
                             int N, unsigned* __restrict__ hist, float* __restrict__ banks) {
    float S[9] = {0}, G[45] = {0};
    for (int i = blockIdx.x * blockDim.x + threadIdx.x; i < N;
         i += gridDim.x * blockDim.x) {
        int v = (coords[3 * i] << 10) | (coords[3 * i + 1] << 5) | coords[3 * i + 2];
        atomicAdd(&hist[v], 1u);
        const float* r = feats + (size_t)i * 9;
        float x[9];
#pragma unroll
        for (int c = 0; c < 9; ++c) { x[c] = r[c]; S[c] += x[c]; }
        int idx = 0;
#pragma unroll
        for (int c = 0; c < 9; ++c)
#pragma unroll
            for (int c2 = 0; c2 <= c; ++c2) { G[idx] = fmaf(x[c], x[c2], G[idx]); ++idx; }
    }
#pragma unroll
    for (int m = 1; m <= 32; m <<= 1) {
#pragma unroll
        for (int c = 0; c < 9; ++c) S[c] += __shfl_xor(S[c], m);
#pragma unroll
        for (int j = 0; j < 45; ++j) G[j] += __shfl_xor(G[j], m);
    }
    if ((threadIdx.x & 63) == 0) {
        float* b = banks + (size_t)(blockIdx.x & 63) * 54;
#pragma unroll
        for (int c = 0; c < 9; ++c) atomicAdd(&b[c], S[c]);
#pragma unroll
        for (int j = 0; j < 45; ++j) atomicAdd(&b[9 + j], G[j]);
    }
}

__global__ void k_fin0(const float* __restrict__ banks, float* __restrict__ SG,
                       const float* __restrict__ g0, const float* __restrict__ be0,
                       float* __restrict__ A0, float* __restrict__ C0, float n) {
    __shared__ float sg[54];
    const int t = threadIdx.x;
    if (t < 54) {
        float s = 0.f;
        for (int b = 0; b < 64; ++b) s += banks[b * 54 + t];
        sg[t] = s; SG[t] = s;
    }
    __syncthreads();
    if (t < 9) {
        float m = sg[t] / n;
        float v = sg[9 + t * (t + 1) / 2 + t] / n - m * m;
        float a = g0[t] * rsqrtf(v + BN_EPS);
        A0[t] = a; C0[t] = be0[t] - m * a;
    }
}

// analytic L1 stats
__global__ void k_fin1(const float* __restrict__ SG,
                       const float* __restrict__ A0, const float* __restrict__ C0,
                       const float* __restrict__ W1, const float* __restrict__ b1,
                       const float* __restrict__ g1, const float* __restrict__ be1,
                       float* __restrict__ A1, float* __restrict__ C1, float n) {
    __shared__ float Sz[9], Gz[81];
    const int t = threadIdx.x;
    if (t < 9) Sz[t] = A0[t] * SG[t] + n * C0[t];
    if (t < 81) {
        const int c = t / 9, c2 = t - 9 * (t / 9);
        const int i = c > c2 ? c : c2, j = c > c2 ? c2 : c;
        const float G = SG[9 + i * (i + 1) / 2 + j];
        Gz[t] = A0[c] * A0[c2] * G + A0[c] * SG[c] * C0[c2]
              + C0[c] * A0[c2] * SG[c2] + n * C0[c] * C0[c2];
    }
    __syncthreads();
    if (t < 64) {
        float wn[9];
#pragma unroll
        for (int c = 0; c < 9; ++c) wn[c] = W1[c * 64 + t];
        float su = 0.f, qq = 0.f;
#pragma unroll
        for (int c = 0; c < 9; ++c) {
            su = fmaf(wn[c], Sz[c], su);
#pragma unroll
            for (int c2 = 0; c2 < 9; ++c2) qq = fmaf(wn[c] * wn[c2], Gz[c * 9 + c2], qq);
        }
        const float bb = b1[t];
        const float mean = (su + n * bb) / n;
        const float q = qq + 2.f * bb * su + n * bb * bb;
        const float var = q / n - mean * mean;
        const float a = g1[t] * rsqrtf(var + BN_EPS);
        A1[t] = a;
        C1[t] = fmaf(a, bb, be1[t] - mean * a);
    }
}

__global__ void k_scan(const unsigned* __restrict__ hist, int* __restrict__ base,
                       unsigned* __restrict__ cursor, int N) {
    __shared__ unsigned part[1024];
    const int t = threadIdx.x;
    unsigned sum = 0;
    for (int j = 0; j < 32; ++j) sum += hist[t * 32 + j];
    part[t] = sum;
    __syncthreads();
    for (int d = 1; d < 1024; d <<= 1) {
        unsigned v = (t >= d) ? part[t - d] : 0u;
        __syncthreads();
        part[t] += v;
        __syncthreads();
    }
    unsigned run = part[t] - sum;
    for (int j = 0; j < 32; ++j) {
        unsigned h = hist[t * 32 + j];
        base[t * 32 + j] = (int)run;
        cursor[t * 32 + j] = run;
        run += h;
    }
    if (t == 1023) base[32768] = (int)run;
}

__global__ void k_scatter2(const int* __restrict__ coords, const float* __restrict__ feats,
                           int N, unsigned* __restrict__ cursor,
                           const float* __restrict__ A0, const float* __restrict__ C0,
                           unsigned short* __restrict__ Xg) {
    float a0[9], c0[9];
#pragma unroll
    for (int c = 0; c < 9; ++c) { a0[c] = A0[c]; c0[c] = C0[c]; }
    for (int i = blockIdx.x * blockDim.x + threadIdx.x; i < N;
         i += gridDim.x * blockDim.x) {
        int v = (coords[3 * i] << 10) | (coords[3 * i + 1] << 5) | coords[3 * i + 2];
        unsigned pos = atomicAdd(&cursor[v], 1u);
        const float* r = feats + (size_t)i * 9;
        s16x8 lo, hi;
#pragma unroll
        for (int c = 0; c < 8; ++c) lo[c] = (short)f2bf(fmaf(r[c], a0[c], c0[c]));
        hi = (s16x8){0, 0, 0, 0, 0, 0, 0, 0};
        hi[0] = (short)f2bf(fmaf(r[8], a0[8], c0[8]));
        *(s16x8*)(Xg + (size_t)pos * 16) = lo;
        *(s16x8*)(Xg + (size_t)pos * 16 + 8) = hi;
    }
}

__global__ void k_fin(const float* __restrict__ part, int nparts, int C,
                      const float* __restrict__ g, const float* __restrict__ be,
                      const float* __restrict__ bias,
                      float* __restrict__ A, float* __restrict__ Cc, float n) {
    int c = threadIdx.x;
    if (c >= C) return;
    float s = 0.f, q = 0.f;
    for (int r = 0; r < nparts; ++r) { s += part[r * 2 * C + c]; q += part[r * 2 * C + C + c]; }
    float m = s / n;
    float v = q / n - m * m;
    float a = g[c] * rsqrtf(v + BN_EPS);
    float cc = be[c] - m * a;
    A[c] = a;
    Cc[c] = bias ? fmaf(a, bias[c], cc) : cc;
}

__global__ void k_coords(float* __restrict__ outc) {
    int v = blockIdx.x * blockDim.x + threadIdx.x;
    if (v < NVOX) {
        outc[3 * v + 0] = (float)(v >> 10);
        outc[3 * v + 1] = (float)((v >> 5) & 31);
        outc[3 * v + 2] = (float)(v & 31);
    }
}

// =====================================================================
// pass2: X -> L1 -> L2 stats.  Hoisted LDS bases + imm offsets.
// =====================================================================
__global__ __launch_bounds__(256) void k_pass2(
    const unsigned short* __restrict__ Xg,
    const unsigned short* __restrict__ wt1, const unsigned short* __restrict__ wt2,
    const float* __restrict__ A1, const float* __restrict__ C1,
    const float* __restrict__ b2,
    float* __restrict__ p2, int N, int nt) {
    __shared__ char act1[2][16384];   // [128][128B] swz, double-buffered
    const int tid = threadIdx.x;
    const int w = tid >> 6, lane = tid & 63, g = lane >> 4, lq = lane & 15;
    const int chb1 = w * 16, chb2 = w * 32;
    const int mask = (lq & 7) << 4;
    char* const a1w  = act1[0] + lq * 128 + (((chb1 + g * 4) * 2) ^ mask);
    char* const a1r0 = act1[0] + lq * 128 + ((g * 16) ^ mask);
    char* const a1r1 = act1[0] + lq * 128 + ((64 + g * 16) ^ mask);

    const s16x8 a1 = *(const s16x8*)(wt1 + (chb1 + lq) * 32 + g * 8);
    s16x8 w2f[2][2];
#pragma unroll
    for (int mt = 0; mt < 2; ++mt)
#pragma unroll
        for (int kc = 0; kc < 2; ++kc)
            w2f[mt][kc] = *(const s16x8*)(wt2 + (size_t)(chb2 + mt * 16 + lq) * 64 + kc * 32 + g * 8);
    const int ch1 = chb1 + g * 4;
    const f32x4 av1 = *(const f32x4*)(A1 + ch1);
    const f32x4 cv1 = *(const f32x4*)(C1 + ch1);
    f32x4 bv2[2];
#pragma unroll
    for (int mt = 0; mt < 2; ++mt) bv2[mt] = *(const f32x4*)(b2 + chb2 + mt * 16 + g * 4);
    f32x4 ps[2], pq[2];
#pragma unroll
    for (int mt = 0; mt < 2; ++mt) { ps[mt] = (f32x4){0.f,0.f,0.f,0.f}; pq[mt] = (f32x4){0.f,0.f,0.f,0.f}; }

    int t = blockIdx.x;
    if (t < nt) {
#pragma unroll
        for (int ct = 0; ct < 8; ++ct) {
            const s16x8 b = *(const s16x8*)(Xg + (size_t)(t * 128 + ct * 16 + lq) * 16 + g * 8);
            f32x4 a = (f32x4){0.f,0.f,0.f,0.f};
            a = __builtin_amdgcn_mfma_f32_16x16x32_bf16(a1, b, a, 0, 0, 0);
            *(s16x4*)(a1w + ct * 2048) = bn_relu_pack(a, av1, cv1);
        }
        __syncthreads();
        int cur = 0;
        while (true) {
            const int tn = t + gridDim.x;
            const bool more = tn < nt;
            const int t0 = t * 128;
            const int co = cur << 14;
            f32x4 acc2[2][8];
#pragma unroll
            for (int mt = 0; mt < 2; ++mt)
#pragma unroll
                for (int ct = 0; ct < 8; ++ct) acc2[mt][ct] = (f32x4){0.f,0.f,0.f,0.f};
#pragma unroll
            for (int kc = 0; kc < 2; ++kc) {
                char* const rb = (kc ? a1r1 : a1r0) + co;
#pragma unroll
                for (int ct = 0; ct < 8; ++ct) {
                    const s16x8 b = *(const s16x8*)(rb + ct * 2048);
#pragma unroll
                    for (int mt = 0; mt < 2; ++mt)
                        acc2[mt][ct] = __builtin_amdgcn_mfma_f32_16x16x32_bf16(w2f[mt][kc], b, acc2[mt][ct], 0, 0, 0);
                }
            }
#pragma unroll
            for (int mt = 0; mt < 2; ++mt)
#pragma unroll
                for (int ct = 0; ct < 8; ++ct) {
                    const bool valid = (t0 + ct * 16 + lq) < N;
#pragma unroll
                    for (int r = 0; r < 4; ++r) {
                        const float h = valid ? (acc2[mt][ct][r] + bv2[mt][r]) : 0.f;
                        ps[mt][r] += h; pq[mt][r] += h * h;
                    }
                }
            if (more) {
                char* const wb = a1w + (co ^ 16384);
#pragma unroll
                for (int ct = 0; ct < 8; ++ct) {
                    const s16x8 b = *(const s16x8*)(Xg + (size_t)(tn * 128 + ct * 16 + lq) * 16 + g * 8);
                    f32x4 a = (f32x4){0.f,0.f,0.f,0.f};
                    a = __builtin_amdgcn_mfma_f32_16x16x32_bf16(a1, b, a, 0, 0, 0);
                    *(s16x4*)(wb + ct * 2048) = bn_relu_pack(a, av1, cv1);
                }
            }
            __syncthreads();
            if (!more) break;
            t = tn; cur ^= 1;
        }
    }
    float* prow = p2 + (blockIdx.x & 63) * 256;
#pragma unroll
    for (int mt = 0; mt < 2; ++mt)
        stats_red<128>(ps[mt], pq[mt], chb2 + mt * 16 + g * 4, prow);
}

// =====================================================================
// pass3: X -> L1 -> L2 -> L3 stats.  Hoisted bases (even/odd-kc pairs).
// =====================================================================
__global__ __launch_bounds__(512) void k_pass3(
    const unsigned short* __restrict__ Xg,
    const unsigned short* __restrict__ wt1, const unsigned short* __restrict__ wt2,
    const unsigned short* __restrict__ wt3,
    const float* __restrict__ A1, const float* __restrict__ C1,
    const float* __restrict__ A2, const float* __restrict__ C2,
    const float* __restrict__ b3,
    float* __restrict__ p3, int N, int nt) {
    __shared__ char act1[8192];    // [64][128B]
    __shared__ char act2[16384];   // [64][256B]
    const int tid = threadIdx.x;
    const int w = tid >> 6, lane = tid & 63, g = lane >> 4, lq = lane & 15;
    const int wm = w >> 1, wn = w & 1;
    const int chb1 = wm * 16, chb2 = w * 16, chb3 = w * 32;
    const int mask = (lq & 7) << 4;
    char* const a1w  = act1 + (wn * 32 + lq) * 128 + (((chb1 + g * 4) * 2) ^ mask);
    char* const a1r0 = act1 + lq * 128 + ((g * 16) ^ mask);
    char* const a1r1 = act1 + lq * 128 + ((64 + g * 16) ^ mask);
    char* const a2w  = act2 + lq * 256 + (((chb2 + g * 4) * 2) ^ mask);
    char* const a2r0 = act2 + lq * 256 + ((g * 16) ^ mask);
    char* const a2r1 = act2 + lq * 256 + ((64 + g * 16) ^ mask);

    const s16x8 a1 = *(const s16x8*)(wt1 + (chb1 + lq) * 32 + g * 8);
    s16x8 w2f[2], w3f[2][4];
#pragma unroll
    for (int kc = 0; kc < 2; ++kc)
        w2f[kc] = *(const s16x8*)(wt2 + (size_t)(chb2 + lq) * 64 + kc * 32 + g * 8);
#pragma unroll
    for (int mt = 0; mt < 2; ++mt)
#pragma unroll
        for (int kc = 0; kc < 4; ++kc)
            w3f[mt][kc] = *(const s16x8*)(wt3 + (size_t)(chb3 + mt * 16 + lq) * 128 + kc * 32 + g * 8);
    const int ch1 = chb1 + g * 4, ch2 = chb2 + g * 4;
    const f32x4 av1 = *(const f32x4*)(A1 + ch1);
    const f32x4 cv1 = *(const f32x4*)(C1 + ch1);
    const f32x4 av2 = *(const f32x4*)(A2 + ch2);
    const f32x4 cv2 = *(const f32x4*)(C2 + ch2);
    f32x4 bv3[2];
#pragma unroll
    for (int mt = 0; mt < 2; ++mt) bv3[mt] = *(const f32x4*)(b3 + chb3 + mt * 16 + g * 4);
    f32x4 ps[2], pq[2];
#pragma unroll
    for (int mt = 0; mt < 2; ++mt) { ps[mt] = (f32x4){0.f,0.f,0.f,0.f}; pq[mt] = (f32x4){0.f,0.f,0.f,0.f}; }

    int t = blockIdx.x;
    if (t < nt) {
#pragma unroll
        for (int ct = 0; ct < 2; ++ct) {
            const int row = wn * 32 + ct * 16 + lq;
            const s16x8 b = *(const s16x8*)(Xg + (size_t)(t * 64 + row) * 16 + g * 8);
            f32x4 a = (f32x4){0.f,0.f,0.f,0.f};
            a = __builtin_amdgcn_mfma_f32_16x16x32_bf16(a1, b, a, 0, 0, 0);
            *(s16x4*)(a1w + ct * 2048) = bn_relu_pack(a, av1, cv1);
        }
        __syncthreads();
        {
            f32x4 acc[4];
#pragma unroll
            for (int ct = 0; ct < 4; ++ct) acc[ct] = (f32x4){0.f,0.f,0.f,0.f};
#pragma unroll
            for (int kc = 0; kc < 2; ++kc) {
                char* const rb = kc ? a1r1 : a1r0;
#pragma unroll
                for (int ct = 0; ct < 4; ++ct) {
                    const s16x8 b = *(const s16x8*)(rb + ct * 2048);
                    acc[ct] = __builtin_amdgcn_mfma_f32_16x16x32_bf16(w2f[kc], b, acc[ct], 0, 0, 0);
                }
            }
#pragma unroll
            for (int ct = 0; ct < 4; ++ct)
                *(s16x4*)(a2w + ct * 4096) = bn_relu_pack(acc[ct], av2, cv2);
        }
        __syncthreads();
        while (true) {
            const int tn = t + gridDim.x;
            const bool more = tn < nt;
            s16x8 xb[2];
            if (more) {
#pragma unroll
                for (int ct = 0; ct < 2; ++ct) {
                    const int row = wn * 32 + ct * 16 + lq;
                    xb[ct] = *(const s16x8*)(Xg + (size_t)(tn * 64 + row) * 16 + g * 8);
                }
            }
            {
                f32x4 acc[2][4];
#pragma unroll
                for (int mt = 0; mt < 2; ++mt)
#pragma unroll
                    for (int ct = 0; ct < 4; ++ct) acc[mt][ct] = (f32x4){0.f,0.f,0.f,0.f};
#pragma unroll
                for (int kc = 0; kc < 4; ++kc) {
                    char* const rb = ((kc & 1) ? a2r1 : a2r0) + (kc >> 1) * 128;
#pragma unroll
                    for (int ct = 0; ct < 4; ++ct) {
                        const s16x8 b = *(const s16x8*)(rb + ct * 4096);
#pragma unroll
                        for (int mt = 0; mt < 2; ++mt)
                            acc[mt][ct] = __builtin_amdgcn_mfma_f32_16x16x32_bf16(w3f[mt][kc], b, acc[mt][ct], 0, 0, 0);
                    }
                }
                const int t0 = t * 64;
#pragma unroll
                for (int mt = 0; mt < 2; ++mt)
#pragma unroll
                    for (int ct = 0; ct < 4; ++ct) {
                        const bool valid = (t0 + ct * 16 + lq) < N;
#pragma unroll
                        for (int r = 0; r < 4; ++r) {
                            const float h = valid ? (acc[mt][ct][r] + bv3[mt][r]) : 0.f;
                            ps[mt][r] += h; pq[mt][r] += h * h;
                        }
                    }
            }
            if (more) {
#pragma unroll
                for (int ct = 0; ct < 2; ++ct) {
                    f32x4 a = (f32x4){0.f,0.f,0.f,0.f};
                    a = __builtin_amdgcn_mfma_f32_16x16x32_bf16(a1, xb[ct], a, 0, 0, 0);
                    *(s16x4*)(a1w + ct * 2048) = bn_relu_pack(a, av1, cv1);
                }
            }
            __syncthreads();
            if (more) {
                f32x4 acc[4];
#pragma unroll
                for (int ct = 0; ct < 4; ++ct) acc[ct] = (f32x4){0.f,0.f,0.f,0.f};
#pragma unroll
                for (int kc = 0; kc < 2; ++kc) {
                    char* const rb = kc ? a1r1 : a1r0;
#pragma unroll
                    for (int ct = 0; ct < 4; ++ct) {
                        const s16x8 b = *(const s16x8*)(rb + ct * 2048);
                        acc[ct] = __builtin_amdgcn_mfma_f32_16x16x32_bf16(w2f[kc], b, acc[ct], 0, 0, 0);
                    }
                }
#pragma unroll
                for (int ct = 0; ct < 4; ++ct)
                    *(s16x4*)(a2w + ct * 4096) = bn_relu_pack(acc[ct], av2, cv2);
            }
            __syncthreads();
            if (!more) break;
            t = tn;
        }
    }
    float* prow = p3 + (blockIdx.x & 63) * 512;
#pragma unroll
    for (int mt = 0; mt < 2; ++mt)
        stats_red<256>(ps[mt], pq[mt], chb3 + mt * 16 + g * 4, prow);
}

// =====================================================================
// pass4: X -> L1..L4 -> segment max.  1024 thr / 16 waves / 16-ch slices.
// Hoisted bases; even/odd-kc base pairs (mask bit 6 collides with kc*64).
// =====================================================================
__global__ __launch_bounds__(1024, 4) void k_pass4(
    const unsigned short* __restrict__ Xg,
    const unsigned short* __restrict__ wt1, const unsigned short* __restrict__ wt2,
    const unsigned short* __restrict__ wt3, const unsigned short* __restrict__ wt4,
    const float* __restrict__ A1, const float* __restrict__ C1,
    const float* __restrict__ A2, const float* __restrict__ C2,
    const float* __restrict__ A3, const float* __restrict__ C3,
    const float* __restrict__ b4,
    const int* __restrict__ base, float* __restrict__ out) {
    extern __shared__ char smem[];
    char* act1 = smem;                  // 8K  [64][128B]
    char* act2 = smem + 8192;           // 16K [64][256B]
    char* act3 = smem + 24576;          // 32K [64][512B]
    char* h4   = smem + 57344;          // 32K [64][512B]

    const int tid = threadIdx.x;
    const int w = tid >> 6, lane = tid & 63, g = lane >> 4, lq = lane & 15;
    const int c1 = (w & 3) * 16, p1 = (w >> 2) * 16;
    const int c2 = (w & 7) * 16, p2 = (w >> 3) * 32;
    const int c3 = w * 16;
    const int mask = (lq & 7) << 4;
    // hoisted bases
    char* const a1w  = act1 + (p1 + lq) * 128 + (((c1 + g * 4) * 2) ^ mask);
    char* const a1r0 = act1 + (p2 + lq) * 128 + ((g * 16) ^ mask);        // + ct*2048 (ct<2)
    char* const a1r1 = act1 + (p2 + lq) * 128 + ((64 + g * 16) ^ mask);
    char* const a2w  = act2 + (p2 + lq) * 256 + (((c2 + g * 4) * 2) ^ mask);  // + ct*4096 (ct<2)
    char* const a2r0 = act2 + lq * 256 + ((g * 16) ^ mask);      // kc even: +(kc>>1)*128 + ct*4096
    char* const a2r1 = act2 + lq * 256 + ((64 + g * 16) ^ mask); // kc odd
    char* const a3w  = act3 + lq * 512 + (((c3 + g * 4) * 2) ^ mask);     // + ct*8192 (ct<4)
    char* const a3r0 = act3 + lq * 512 + ((g * 16) ^ mask);      // kc even: +(kc>>1)*128 + ct*8192
    char* const a3r1 = act3 + lq * 512 + ((64 + g * 16) ^ mask); // kc odd
    char* const h4w  = h4 + lq * 512 + (((c3 + g * 4) * 2) ^ mask);       // + ct*8192

    const int vb = blockIdx.x * 32;
    const int pstart = base[vb], pend = base[vb + 32];
    const int chgrp = tid & 31, slot = tid >> 5;
    const int vlo = base[vb + slot], vhi = base[vb + slot + 1];

    const s16x8 a1 = *(const s16x8*)(wt1 + (c1 + lq) * 32 + g * 8);
    s16x8 w2f[2], w3f[4], w4f[8];
#pragma unroll
    for (int kc = 0; kc < 2; ++kc)
        w2f[kc] = *(const s16x8*)(wt2 + (size_t)(c2 + lq) * 64 + kc * 32 + g * 8);
#pragma unroll
    for (int kc = 0; kc < 4; ++kc)
        w3f[kc] = *(const s16x8*)(wt3 + (size_t)(c3 + lq) * 128 + kc * 32 + g * 8);
#pragma unroll
    for (int kc = 0; kc < 8; ++kc)
        w4f[kc] = *(const s16x8*)(wt4 + (size_t)(c3 + lq) * 256 + kc * 32 + g * 8);

    const f32x4 av1 = *(const f32x4*)(A1 + c1 + g * 4);
    const f32x4 cv1 = *(const f32x4*)(C1 + c1 + g * 4);
    const f32x4 av2 = *(const f32x4*)(A2 + c2 + g * 4);
    const f32x4 cv2 = *(const f32x4*)(C2 + c2 + g * 4);
    const f32x4 av3 = *(const f32x4*)(A3 + c3 + g * 4);
    const f32x4 cv3 = *(const f32x4*)(C3 + c3 + g * 4);
    const f32x4 bv4 = *(const f32x4*)(b4 + c3 + g * 4);

    float rmax[8];
#pragma unroll
    for (int j = 0; j < 8; ++j) rmax[j] = -INFINITY;

    if (pstart < pend) {
        {
            const s16x8 b = *(const s16x8*)(Xg + (size_t)(pstart + p1 + lq) * 16 + g * 8);
            f32x4 a = (f32x4){0.f,0.f,0.f,0.f};
            a = __builtin_amdgcn_mfma_f32_16x16x32_bf16(a1, b, a, 0, 0, 0);
            *(s16x4*)a1w = bn_relu_pack(a, av1, cv1);
        }
        __syncthreads();
        {
            f32x4 acc[2];
#pragma unroll
            for (int ct = 0; ct < 2; ++ct) acc[ct] = (f32x4){0.f,0.f,0.f,0.f};
#pragma unroll
            for (int kc = 0; kc < 2; ++kc) {
                char* const rb = kc ? a1r1 : a1r0;
#pragma unroll
                for (int ct = 0; ct < 2; ++ct) {
                    const s16x8 b = *(const s16x8*)(rb + ct * 2048);
                    acc[ct] = __builtin_amdgcn_mfma_f32_16x16x32_bf16(w2f[kc], b, acc[ct], 0, 0, 0);
                }
            }
#pragma unroll
            for (int ct = 0; ct < 2; ++ct)
                *(s16x4*)(a2w + ct * 4096) = bn_relu_pack(acc[ct], av2, cv2);
        }
        __syncthreads();

        int lt = pstart;
        for (int t0 = pstart; t0 < pend; t0 += 64) {
            const int nxt = t0 + 64;
            const bool more = nxt < pend;
            // ===== phase A: L3(t0) + segmax(t0-64) + X/L1(nxt) =====
            s16x8 xb;
            if (more)
                xb = *(const s16x8*)(Xg + (size_t)(nxt + p1 + lq) * 16 + g * 8);
            {
                f32x4 acc[4];
#pragma unroll
                for (int ct = 0; ct < 4; ++ct) acc[ct] = (f32x4){0.f,0.f,0.f,0.f};
#pragma unroll
                for (int kc = 0; kc < 4; ++kc) {
                    char* const rb = ((kc & 1) ? a2r1 : a2r0) + (kc >> 1) * 128;
#pragma unroll
                    for (int ct = 0; ct < 4; ++ct) {
                        const s16x8 b = *(const s16x8*)(rb + ct * 4096);
                        acc[ct] = __builtin_amdgcn_mfma_f32_16x16x32_bf16(w3f[kc], b, acc[ct], 0, 0, 0);
                    }
                }
#pragma unroll
                for (int ct = 0; ct < 4; ++ct)
                    *(s16x4*)(a3w + ct * 8192) = bn_relu_pack(acc[ct], av3, cv3);
            }
            if (t0 > pstart) {
                const int tm = t0 - 64;
                const int lo = max(vlo, tm), hi = min(vhi, tm + 64);
                for (int p = lo; p < hi; ++p) {
                    const int row = p - tm;
                    const s16x8 hv = *(const s16x8*)(h4 + row * 512 + ((chgrp * 16) ^ ((row & 7) << 4)));
#pragma unroll
                    for (int j = 0; j < 8; ++j)
                        rmax[j] = fmaxf(rmax[j], bf2f((unsigned short)hv[j]));
                }
            }
            if (more) {
                f32x4 a = (f32x4){0.f,0.f,0.f,0.f};
                a = __builtin_amdgcn_mfma_f32_16x16x32_bf16(a1, xb, a, 0, 0, 0);
                *(s16x4*)a1w = bn_relu_pack(a, av1, cv1);
            }
            __syncthreads();
            // ===== phase B: L2(nxt) + L4(t0) -> h4 =====
            if (more) {
                f32x4 acc[2];
#pragma unroll
                for (int ct = 0; ct < 2; ++ct) acc[ct] = (f32x4){0.f,0.f,0.f,0.f};
#pragma unroll
                for (int kc = 0; kc < 2; ++kc) {
                    char* const rb = kc ? a1r1 : a1r0;
#pragma unroll
                    for (int ct = 0; ct < 2; ++ct) {
                        const s16x8 b = *(const s16x8*)(rb + ct * 2048);
                        acc[ct] = __builtin_amdgcn_mfma_f32_16x16x32_bf16(w2f[kc], b, acc[ct], 0, 0, 0);
                    }
                }
#pragma unroll
                for (int ct = 0; ct < 2; ++ct)
                    *(s16x4*)(a2w + ct * 4096) = bn_relu_pack(acc[ct], av2, cv2);
            }
            {
                f32x4 acc[4];
#pragma unroll
                for (int ct = 0; ct < 4; ++ct) acc[ct] = (f32x4){0.f,0.f,0.f,0.f};
#pragma unroll
                for (int kc = 0; kc < 8; ++kc) {
                    char* const rb = ((kc & 1) ? a3r1 : a3r0) + (kc >> 1) * 128;
#pragma unroll
                    for (int ct = 0; ct < 4; ++ct) {
                        const s16x8 b = *(const s16x8*)(rb + ct * 8192);
                        acc[ct] = __builtin_amdgcn_mfma_f32_16x16x32_bf16(w4f[kc], b, acc[ct], 0, 0, 0);
                    }
                }
#pragma unroll
                for (int ct = 0; ct < 4; ++ct) {
                    s16x4 pk;
#pragma unroll
                    for (int r = 0; r < 4; ++r) pk[r] = (short)f2bf(acc[ct][r] + bv4[r]);
                    *(s16x4*)(h4w + ct * 8192) = pk;
                }
            }
            __syncthreads();
            lt = t0;
        }
        // drain
        {
            const int lo = max(vlo, lt), hi = min(vhi, lt + 64);
            for (int p = lo; p < hi; ++p) {
                const int row = p - lt;
                const s16x8 hv = *(const s16x8*)(h4 + row * 512 + ((chgrp * 16) ^ ((row & 7) << 4)));
#pragma unroll
                for (int j = 0; j < 8; ++j)
                    rmax[j] = fmaxf(rmax[j], bf2f((unsigned short)hv[j]));
            }
        }
    }
    float* orow = out + (size_t)(vb + slot) * 256 + chgrp * 8;
    f32x4 o0, o1;
#pragma unroll
    for (int j = 0; j < 4; ++j) { o0[j] = rmax[j]; o1[j] = rmax[4 + j]; }
    *(f32x4*)orow = o0;
    *(f32x4*)(orow + 4) = o1;
}

extern "C" void kernel_launch(void* const* d_in, const int* in_sizes, int n_in,
                              void* d_out, int out_size, void* d_ws, size_t ws_size,
                              hipStream_t stream) {
    const float* feats = (const float*)d_in[0];
    const int* coords = (const int*)d_in[1];
    const float* g0 = (const float*)d_in[3];
    const float* be0 = (const float*)d_in[4];
    const float* W1 = (const float*)d_in[5];
    const float* b1 = (const float*)d_in[6];
    const float* g1 = (const float*)d_in[7];
    const float* be1 = (const float*)d_in[8];
    const float* W2 = (const float*)d_in[9];
    const float* b2 = (const float*)d_in[10];
    const float* g2 = (const float*)d_in[11];
    const float* be2 = (const float*)d_in[12];
    const float* W3 = (const float*)d_in[13];
    const float* b3 = (const float*)d_in[14];
    const float* g3 = (const float*)d_in[15];
    const float* be3 = (const float*)d_in[16];
    const float* W4 = (const float*)d_in[17];
    const float* b4 = (const float*)d_in[18];
    float* out = (float*)d_out;
    char* ws = (char*)d_ws;

    const int N = in_sizes[0] / 9;
    const float fN = (float)N;
    const int nt128 = (N + 127) / 128;
    const int nt64 = (N + 63) / 64;

    unsigned short* Xg = (unsigned short*)(ws + X_OFF);
    const unsigned short* wt1 = (const unsigned short*)(ws + WT1_OFF);
    const unsigned short* wt2 = (const unsigned short*)(ws + WT2_OFF);
    const unsigned short* wt3 = (const unsigned short*)(ws + WT3_OFF);
    const unsigned short* wt4 = (const unsigned short*)(ws + WT4_OFF);
    float* A0 = (float*)(ws + A0_OFF); float* C0 = (float*)(ws + C0_OFF);
    float* A1 = (float*)(ws + A1_OFF); float* C1 = (float*)(ws + C1_OFF);
    float* A2 = (float*)(ws + A2_OFF); float* C2 = (float*)(ws + C2_OFF);
    float* A3 = (float*)(ws + A3_OFF); float* C3 = (float*)(ws + C3_OFF);

    hipMemsetAsync(ws, 0, PAR_END, stream);
    hipMemsetAsync(ws + HIST_OFF, 0, 131072, stream);
    {   // zero X padding rows (pass kernels may read past N)
        const size_t rows = (size_t)nt128 * 128;
        hipMemsetAsync(ws + X_OFF + (size_t)N * 32u, 0,
                       (rows - (size_t)N) * 32u + 8192u, stream);
    }

    hipFuncSetAttribute((const void*)k_pass4,
        hipFuncAttributeMaxDynamicSharedMemorySize, 90112);

    k_prepw<<<128, TPB, 0, stream>>>(W1, W2, W3, W4,
        (unsigned short*)(ws + WT1_OFF), (unsigned short*)(ws + WT2_OFF),
        (unsigned short*)(ws + WT3_OFF), (unsigned short*)(ws + WT4_OFF));
    k_hist_stats<<<1024, TPB, 0, stream>>>(coords, feats, N,
        (unsigned*)(ws + HIST_OFF), (float*)(ws + P1_OFF));
    k_fin0<<<1, 64, 0, stream>>>((const float*)(ws + P1_OFF), (float*)(ws + P0_OFF),
                                 g0, be0, A0, C0, fN);
    k_fin1<<<1, 128, 0, stream>>>((const float*)(ws + P0_OFF), A0, C0,
                                  W1, b1, g1, be1, A1, C1, fN);
    k_scan<<<1, 1024, 0, stream>>>((const unsigned*)(ws + HIST_OFF),
                                   (int*)(ws + BASE_OFF), (unsigned*)(ws + CURS_OFF), N);
    k_scatter2<<<1024, TPB, 0, stream>>>(coords, feats, N, (unsigned*)(ws + CURS_OFF),
                                         A0, C0, Xg);
    k_coords<<<(NVOX + TPB - 1) / TPB, TPB, 0, stream>>>(out + (size_t)NVOX * 256);

    k_pass2<<<2048, 256, 0, stream>>>(Xg, wt1, wt2, A1, C1, b2,
                                      (float*)(ws + P2_OFF), N, nt128);
    k_fin<<<1, TPB, 0, stream>>>((const float*)(ws + P2_OFF), 64, 128, g2, be2, b2,
                                 A2, C2, fN);

    k_pass3<<<2048, 512, 0, stream>>>(Xg, wt1, wt2, wt3, A1, C1, A2, C2, b3,
                                      (float*)(ws + P3_OFF), N, nt64);
    k_fin<<<1, TPB, 0, stream>>>((const float*)(ws + P3_OFF), 64, 256, g3, be3, b3,
                                 A3, C3, fN);

    k_pass4<<<NVOX / 32, 1024, 90112, stream>>>(Xg, wt1, wt2, wt3, wt4,
        A1, C1, A2, C2, A3, C3, b4, (const int*)(ws + BASE_OFF), out);
}